// Round 2
// baseline (3038.822 us; speedup 1.0000x reference)
//
#include <hip/hip_runtime.h>

// GIN 2-layer forward on MI355X (gfx950).
// Input dtype (bf16 vs fp32) auto-detected at runtime, device-side.
// Internal compute fp32. Output written in the detected dtype.

#define N_NODES 50000
#define N_EDGES 800000
#define DIM 128
#define BN_EPS 1e-5f

__device__ __forceinline__ float bf2f(unsigned short u) {
  union { unsigned u32; float f; } c;
  c.u32 = ((unsigned)u) << 16;
  return c.f;
}
__device__ __forceinline__ unsigned short f2bf(float f) {
  union { float f; unsigned u32; } c;
  c.f = f;
  unsigned u = c.u32;
  return (unsigned short)((u + 0x7fffu + ((u >> 16) & 1u)) >> 16);  // RNE
}

// ---- dtype detector: bf16 buffer => every even ushort is a bf16 of N(0,1) ----
__global__ void detect_kernel(const unsigned short* __restrict__ xs,
                              int* __restrict__ flag) {
  __shared__ int oks[64];
  int t = threadIdx.x;
  unsigned short u = xs[t * 2];
  int e = (u >> 7) & 0xFF;
  oks[t] = ((e >= 96 && e <= 134) || ((u & 0x7FFFu) == 0)) ? 1 : 0;
  __syncthreads();
  if (t == 0) {
    int c = 0;
    for (int i = 0; i < 64; ++i) c += oks[i];
    *flag = (c >= 56) ? 1 : 0;  // 1 = bf16, 0 = fp32
  }
}

// ---- convert the 4 weight matrices into fp32 block P ----
__global__ __launch_bounds__(256) void wcvt_w_kernel(
    const void* w0, const void* w1, const void* w2, const void* w3,
    float* __restrict__ P, const int* __restrict__ flagp) {
  const void* src = (blockIdx.y == 0) ? w0 : (blockIdx.y == 1) ? w1
                  : (blockIdx.y == 2) ? w2 : w3;
  float* dst = P + (size_t)blockIdx.y * (DIM * DIM);
  int i = (blockIdx.x * 256 + threadIdx.x) * 4;
  if (i >= DIM * DIM) return;
  if (*flagp) {
    const unsigned short* s = (const unsigned short*)src;
    dst[i + 0] = bf2f(s[i + 0]);
    dst[i + 1] = bf2f(s[i + 1]);
    dst[i + 2] = bf2f(s[i + 2]);
    dst[i + 3] = bf2f(s[i + 3]);
  } else {
    const float* s = (const float*)src;
    dst[i + 0] = s[i + 0];
    dst[i + 1] = s[i + 1];
    dst[i + 2] = s[i + 2];
    dst[i + 3] = s[i + 3];
  }
}

// ---- convert the 10 length-128 param vectors into fp32 ----
struct VPtrs { const void* p[10]; };

__global__ void wcvt_v_kernel(VPtrs vp, float* __restrict__ dst,
                              const int* __restrict__ flagp) {
  int bf = *flagp;
  for (int j = threadIdx.x; j < 10 * DIM; j += 256) {
    int vec = j >> 7, idx = j & 127;
    float v;
    if (bf) v = bf2f(((const unsigned short*)vp.p[vec])[idx]);
    else    v = ((const float*)vp.p[vec])[idx];
    dst[j] = v;
  }
}

// ---- scatter-add: agg[row[e]] += x[col[e]]  (x in detected dtype) ----
__global__ __launch_bounds__(256) void scatter_x_kernel(
    const void* __restrict__ xv, const int* __restrict__ row,
    const int* __restrict__ col, float* __restrict__ agg,
    const int* __restrict__ flagp) {
  int t = blockIdx.x * 256 + threadIdx.x;
  int e = t >> 5;
  if (e >= N_EDGES) return;
  int lane = t & 31;
  int r = row[e], c = col[e];
  int ch = lane * 4;
  float v0, v1, v2, v3;
  if (*flagp) {
    const unsigned short* x = (const unsigned short*)xv;
    ushort4 u = *(const ushort4*)(x + (size_t)c * DIM + ch);
    v0 = bf2f(u.x); v1 = bf2f(u.y); v2 = bf2f(u.z); v3 = bf2f(u.w);
  } else {
    const float* x = (const float*)xv;
    float4 u = *(const float4*)(x + (size_t)c * DIM + ch);
    v0 = u.x; v1 = u.y; v2 = u.z; v3 = u.w;
  }
  float* dst = agg + (size_t)r * DIM + ch;
  unsafeAtomicAdd(dst + 0, v0);
  unsafeAtomicAdd(dst + 1, v1);
  unsafeAtomicAdd(dst + 2, v2);
  unsafeAtomicAdd(dst + 3, v3);
}

// ---- scatter-add fused relu(BN): agg[row[e]] += relu(h[col[e]]*sc+sh) ----
__global__ __launch_bounds__(256) void scatter_h_kernel(
    const float* __restrict__ h, const int* __restrict__ row,
    const int* __restrict__ col, const float* __restrict__ ss,
    float* __restrict__ agg) {
  int t = blockIdx.x * 256 + threadIdx.x;
  int e = t >> 5;
  if (e >= N_EDGES) return;
  int lane = t & 31;
  int r = row[e], c = col[e];
  int ch = lane * 4;
  float4 v = *(const float4*)(h + (size_t)c * DIM + ch);
  float4 sc = *(const float4*)(ss + ch);
  float4 sh = *(const float4*)(ss + DIM + ch);
  float* dst = agg + (size_t)r * DIM + ch;
  unsafeAtomicAdd(dst + 0, fmaxf(v.x * sc.x + sh.x, 0.f));
  unsafeAtomicAdd(dst + 1, fmaxf(v.y * sc.y + sh.y, 0.f));
  unsafeAtomicAdd(dst + 2, fmaxf(v.z * sc.z + sh.z, 0.f));
  unsafeAtomicAdd(dst + 3, fmaxf(v.w * sc.w + sh.w, 0.f));
}

// ---- BN finalize: (sum, sumsq) -> per-channel scale/shift ----
__global__ void bn_fin_kernel(const float* __restrict__ stats,
                              const float* __restrict__ g,
                              const float* __restrict__ be,
                              float* __restrict__ ss) {
  int c = threadIdx.x;
  const float invN = 1.0f / (float)N_NODES;
  float m = stats[c] * invN;
  float v = stats[DIM + c] * invN - m * m;
  float scale = g[c] * rsqrtf(v + BN_EPS);
  ss[c] = scale;
  ss[DIM + c] = be[c] - m * scale;
}

// ---- tiled GEMM: C[32 x 128] = op(A) @ W + bias, optional fused BN stats ----
__global__ __launch_bounds__(256) void gemm_kernel(
    const void* __restrict__ Ap, const float* __restrict__ agg,
    const float* __restrict__ W, const float* __restrict__ bias,
    const float* __restrict__ ss, void* __restrict__ Cp,
    float* __restrict__ stats, const int* __restrict__ flagp,
    int a_input, int add_agg, int transform, int out_ext, int do_stats) {
  __shared__ float AsT[128 * 36];  // A tile transposed [k][row], stride 36
  const int tid = threadIdx.x;
  const int row0 = blockIdx.x * 32;
  const int bf = *flagp;

  for (int i = 0; i < 4; ++i) {
    int idx4 = tid + i * 256;
    int lrow = idx4 >> 5;
    int ch = (idx4 & 31) * 4;
    int grow = row0 + lrow;
    float4 v = make_float4(0.f, 0.f, 0.f, 0.f);
    if (grow < N_NODES) {
      if (a_input && bf) {
        const unsigned short* A = (const unsigned short*)Ap;
        ushort4 u = *(const ushort4*)(A + (size_t)grow * DIM + ch);
        v = make_float4(bf2f(u.x), bf2f(u.y), bf2f(u.z), bf2f(u.w));
      } else {
        v = *(const float4*)((const float*)Ap + (size_t)grow * DIM + ch);
      }
      if (transform) {
        float4 sc = *(const float4*)(ss + ch);
        float4 sh = *(const float4*)(ss + DIM + ch);
        v.x = fmaxf(v.x * sc.x + sh.x, 0.f);
        v.y = fmaxf(v.y * sc.y + sh.y, 0.f);
        v.z = fmaxf(v.z * sc.z + sh.z, 0.f);
        v.w = fmaxf(v.w * sc.w + sh.w, 0.f);
      }
      if (add_agg) {
        float4 a = *(const float4*)(agg + (size_t)grow * DIM + ch);
        v.x += a.x; v.y += a.y; v.z += a.z; v.w += a.w;
      }
    }
    AsT[(ch + 0) * 36 + lrow] = v.x;
    AsT[(ch + 1) * 36 + lrow] = v.y;
    AsT[(ch + 2) * 36 + lrow] = v.z;
    AsT[(ch + 3) * 36 + lrow] = v.w;
  }
  __syncthreads();

  const int rg = tid >> 5, cg = tid & 31;
  const int r0 = rg * 4, c0 = cg * 4;
  float acc[4][4] = {};
  const float* wp = W + c0;
#pragma unroll 8
  for (int k = 0; k < 128; ++k) {
    float4 a = *(const float4*)(&AsT[k * 36 + r0]);
    float4 b = *(const float4*)(wp + k * 128);
    acc[0][0] = fmaf(a.x, b.x, acc[0][0]);
    acc[0][1] = fmaf(a.x, b.y, acc[0][1]);
    acc[0][2] = fmaf(a.x, b.z, acc[0][2]);
    acc[0][3] = fmaf(a.x, b.w, acc[0][3]);
    acc[1][0] = fmaf(a.y, b.x, acc[1][0]);
    acc[1][1] = fmaf(a.y, b.y, acc[1][1]);
    acc[1][2] = fmaf(a.y, b.z, acc[1][2]);
    acc[1][3] = fmaf(a.y, b.w, acc[1][3]);
    acc[2][0] = fmaf(a.z, b.x, acc[2][0]);
    acc[2][1] = fmaf(a.z, b.y, acc[2][1]);
    acc[2][2] = fmaf(a.z, b.z, acc[2][2]);
    acc[2][3] = fmaf(a.z, b.w, acc[2][3]);
    acc[3][0] = fmaf(a.w, b.x, acc[3][0]);
    acc[3][1] = fmaf(a.w, b.y, acc[3][1]);
    acc[3][2] = fmaf(a.w, b.z, acc[3][2]);
    acc[3][3] = fmaf(a.w, b.w, acc[3][3]);
  }

  float4 bb = *(const float4*)(bias + c0);
  for (int i = 0; i < 4; ++i) {
    acc[i][0] += bb.x; acc[i][1] += bb.y; acc[i][2] += bb.z; acc[i][3] += bb.w;
  }

  for (int i = 0; i < 4; ++i) {
    int grow = row0 + r0 + i;
    if (grow < N_NODES) {
      if (out_ext && bf) {
        ushort4 o;
        o.x = f2bf(acc[i][0]); o.y = f2bf(acc[i][1]);
        o.z = f2bf(acc[i][2]); o.w = f2bf(acc[i][3]);
        *(ushort4*)((unsigned short*)Cp + (size_t)grow * DIM + c0) = o;
      } else {
        *(float4*)((float*)Cp + (size_t)grow * DIM + c0) =
            make_float4(acc[i][0], acc[i][1], acc[i][2], acc[i][3]);
      }
    }
  }

  if (do_stats) {
    __syncthreads();  // done reading AsT; reuse as reduction scratch
    float* reds = AsT;         // [8][128]
    float* redq = AsT + 1024;  // [8][128]
    for (int j = 0; j < 4; ++j) {
      float s = 0.f, q = 0.f;
      for (int i = 0; i < 4; ++i) {
        if (row0 + r0 + i < N_NODES) {
          float t = acc[i][j];
          s += t; q += t * t;
        }
      }
      reds[rg * 128 + c0 + j] = s;
      redq[rg * 128 + c0 + j] = q;
    }
    __syncthreads();
    if (tid < 128) {
      float s = 0.f, q = 0.f;
      for (int g8 = 0; g8 < 8; ++g8) {
        s += reds[g8 * 128 + tid];
        q += redq[g8 * 128 + tid];
      }
      unsafeAtomicAdd(&stats[tid], s);
      unsafeAtomicAdd(&stats[DIM + tid], q);
    }
  }
}

extern "C" void kernel_launch(void* const* d_in, const int* in_sizes, int n_in,
                              void* d_out, int out_size, void* d_ws, size_t ws_size,
                              hipStream_t stream) {
  const void* x  = d_in[0];
  const int* row = (const int*)d_in[1];
  const int* col = (const int*)d_in[2];

  const size_t ND = (size_t)N_NODES * DIM;
  float* ws    = (float*)d_ws;
  float* agg   = ws;                   // ND
  float* h1    = agg + ND;             // ND
  float* h2    = h1 + ND;              // ND
  float* P     = h2 + ND;              // 4*128*128 fp32 weights
  float* PV    = P + 4 * DIM * DIM;    // 10*128 fp32 param vectors
  float* stats = PV + 10 * DIM;        // 3*256
  float* ss    = stats + 3 * 256;      // 3*256
  int*   flag  = (int*)(ss + 3 * 256); // 1

  float* c0_b1f = PV + 0 * DIM; float* c0_gf  = PV + 1 * DIM;
  float* c0_bef = PV + 2 * DIM; float* c0_b2f = PV + 3 * DIM;
  float* bn0_gf = PV + 4 * DIM; float* bn0_bef= PV + 5 * DIM;
  float* c1_b1f = PV + 6 * DIM; float* c1_gf  = PV + 7 * DIM;
  float* c1_bef = PV + 8 * DIM; float* c1_b2f = PV + 9 * DIM;

  const int gemm_grid = (N_NODES + 31) / 32;   // 1563
  const int scat_grid = (N_EDGES * 32) / 256;  // 100000

  detect_kernel<<<1, 64, 0, stream>>>((const unsigned short*)x, flag);

  wcvt_w_kernel<<<dim3(16, 4), 256, 0, stream>>>(d_in[3], d_in[7], d_in[11],
                                                 d_in[15], P, flag);
  VPtrs vp;
  vp.p[0] = d_in[4];  vp.p[1] = d_in[5];  vp.p[2] = d_in[6];  vp.p[3] = d_in[8];
  vp.p[4] = d_in[9];  vp.p[5] = d_in[10]; vp.p[6] = d_in[12]; vp.p[7] = d_in[13];
  vp.p[8] = d_in[14]; vp.p[9] = d_in[16];
  wcvt_v_kernel<<<1, 256, 0, stream>>>(vp, PV, flag);

  hipMemsetAsync(agg, 0, ND * sizeof(float), stream);
  hipMemsetAsync(stats, 0, 3 * 256 * sizeof(float), stream);

  // ---- conv0 ----
  scatter_x_kernel<<<scat_grid, 256, 0, stream>>>(x, row, col, agg, flag);
  gemm_kernel<<<gemm_grid, 256, 0, stream>>>(
      x, agg, P + 0 * DIM * DIM, c0_b1f, nullptr, h1, stats + 0, flag,
      1, 1, 0, 0, 1);
  bn_fin_kernel<<<1, 128, 0, stream>>>(stats + 0, c0_gf, c0_bef, ss + 0);
  gemm_kernel<<<gemm_grid, 256, 0, stream>>>(
      h1, nullptr, P + 1 * DIM * DIM, c0_b2f, ss + 0, h2, stats + 256, flag,
      0, 0, 1, 0, 1);
  bn_fin_kernel<<<1, 128, 0, stream>>>(stats + 256, bn0_gf, bn0_bef, ss + 256);

  // ---- conv1 ----
  hipMemsetAsync(agg, 0, ND * sizeof(float), stream);
  scatter_h_kernel<<<scat_grid, 256, 0, stream>>>(h2, row, col, ss + 256, agg);
  gemm_kernel<<<gemm_grid, 256, 0, stream>>>(
      h2, agg, P + 2 * DIM * DIM, c1_b1f, ss + 256, h1, stats + 512, flag,
      0, 1, 1, 0, 1);
  bn_fin_kernel<<<1, 128, 0, stream>>>(stats + 512, c1_gf, c1_bef, ss + 512);
  gemm_kernel<<<gemm_grid, 256, 0, stream>>>(
      h1, nullptr, P + 3 * DIM * DIM, c1_b2f, ss + 512, d_out, nullptr, flag,
      0, 0, 1, 1, 0);
}

// Round 3
// 570.084 us; speedup vs baseline: 5.3305x; 5.3305x over previous
//
#include <hip/hip_runtime.h>

// GIN 2-layer forward on MI355X (gfx950). Round 3: scatter-atomics replaced
// by on-device CSR build + per-wave gather (no fp32 atomics on agg).
// Input dtype (bf16 vs fp32) auto-detected at runtime, device-side.

#define N_NODES 50000
#define N_EDGES 800000
#define DIM 128
#define BN_EPS 1e-5f
#define NB 196  // ceil(N_NODES/256)

__device__ __forceinline__ float bf2f(unsigned short u) {
  union { unsigned u32; float f; } c;
  c.u32 = ((unsigned)u) << 16;
  return c.f;
}
__device__ __forceinline__ unsigned short f2bf(float f) {
  union { float f; unsigned u32; } c;
  c.f = f;
  unsigned u = c.u32;
  return (unsigned short)((u + 0x7fffu + ((u >> 16) & 1u)) >> 16);  // RNE
}

// ---- dtype detector: bf16 buffer => every even ushort is a bf16 of N(0,1) ----
__global__ void detect_kernel(const unsigned short* __restrict__ xs,
                              int* __restrict__ flag) {
  __shared__ int oks[64];
  int t = threadIdx.x;
  unsigned short u = xs[t * 2];
  int e = (u >> 7) & 0xFF;
  oks[t] = ((e >= 96 && e <= 134) || ((u & 0x7FFFu) == 0)) ? 1 : 0;
  __syncthreads();
  if (t == 0) {
    int c = 0;
    for (int i = 0; i < 64; ++i) c += oks[i];
    *flag = (c >= 56) ? 1 : 0;  // 1 = bf16, 0 = fp32
  }
}

// ---- convert the 4 weight matrices into fp32 block P ----
__global__ __launch_bounds__(256) void wcvt_w_kernel(
    const void* w0, const void* w1, const void* w2, const void* w3,
    float* __restrict__ P, const int* __restrict__ flagp) {
  const void* src = (blockIdx.y == 0) ? w0 : (blockIdx.y == 1) ? w1
                  : (blockIdx.y == 2) ? w2 : w3;
  float* dst = P + (size_t)blockIdx.y * (DIM * DIM);
  int i = (blockIdx.x * 256 + threadIdx.x) * 4;
  if (i >= DIM * DIM) return;
  if (*flagp) {
    const unsigned short* s = (const unsigned short*)src;
    dst[i + 0] = bf2f(s[i + 0]);
    dst[i + 1] = bf2f(s[i + 1]);
    dst[i + 2] = bf2f(s[i + 2]);
    dst[i + 3] = bf2f(s[i + 3]);
  } else {
    const float* s = (const float*)src;
    dst[i + 0] = s[i + 0];
    dst[i + 1] = s[i + 1];
    dst[i + 2] = s[i + 2];
    dst[i + 3] = s[i + 3];
  }
}

// ---- convert the 10 length-128 param vectors into fp32 ----
struct VPtrs { const void* p[10]; };

__global__ void wcvt_v_kernel(VPtrs vp, float* __restrict__ dst,
                              const int* __restrict__ flagp) {
  int bf = *flagp;
  for (int j = threadIdx.x; j < 10 * DIM; j += 256) {
    int vec = j >> 7, idx = j & 127;
    float v;
    if (bf) v = bf2f(((const unsigned short*)vp.p[vec])[idx]);
    else    v = ((const float*)vp.p[vec])[idx];
    dst[j] = v;
  }
}

// ================= CSR build =================
__global__ __launch_bounds__(256) void deg_kernel(
    const int* __restrict__ row, int* __restrict__ deg) {
  int e = blockIdx.x * 256 + threadIdx.x;
  if (e < N_EDGES) atomicAdd(&deg[row[e]], 1);
}

__global__ __launch_bounds__(256) void bsum_kernel(
    const int* __restrict__ deg, int* __restrict__ bsum) {
  __shared__ int s[256];
  int i = blockIdx.x * 256 + threadIdx.x;
  s[threadIdx.x] = (i < N_NODES) ? deg[i] : 0;
  __syncthreads();
  for (int d = 128; d > 0; d >>= 1) {
    if (threadIdx.x < d) s[threadIdx.x] += s[threadIdx.x + d];
    __syncthreads();
  }
  if (threadIdx.x == 0) bsum[blockIdx.x] = s[0];
}

__global__ __launch_bounds__(256) void bscan_kernel(
    const int* __restrict__ bsum, int* __restrict__ bscan) {
  __shared__ int s[256];
  int t = threadIdx.x;
  int v = (t < NB) ? bsum[t] : 0;
  s[t] = v;
  __syncthreads();
  for (int d = 1; d < 256; d <<= 1) {
    int tv = (t >= d) ? s[t - d] : 0;
    __syncthreads();
    s[t] += tv;
    __syncthreads();
  }
  if (t < NB) bscan[t] = s[t] - v;  // exclusive
}

__global__ __launch_bounds__(256) void offs_kernel(
    const int* __restrict__ deg, const int* __restrict__ bscan,
    int* __restrict__ offs, int* __restrict__ cursor) {
  __shared__ int s[256];
  int t = threadIdx.x;
  int i = blockIdx.x * 256 + t;
  int v = (i < N_NODES) ? deg[i] : 0;
  s[t] = v;
  __syncthreads();
  for (int d = 1; d < 256; d <<= 1) {
    int tv = (t >= d) ? s[t - d] : 0;
    __syncthreads();
    s[t] += tv;
    __syncthreads();
  }
  if (i < N_NODES) {
    int excl = bscan[blockIdx.x] + s[t] - v;
    offs[i] = excl;
    cursor[i] = excl;
    if (i == N_NODES - 1) offs[N_NODES] = excl + v;
  }
}

__global__ __launch_bounds__(256) void binedge_kernel(
    const int* __restrict__ row, const int* __restrict__ col,
    int* __restrict__ cursor, int* __restrict__ csr_col) {
  int e = blockIdx.x * 256 + threadIdx.x;
  if (e < N_EDGES) {
    int slot = atomicAdd(&cursor[row[e]], 1);
    csr_col[slot] = col[e];
  }
}

// ================= gather aggregation =================
// One wave (64 lanes) per node; lane owns channels [2*lane, 2*lane+1].
// mode 0: src is the external input (dtype per flag), no transform.
// mode 1: src is fp32, apply relu(v*sc + sh) per neighbor (ss scale/shift).
__global__ __launch_bounds__(256) void gather_kernel(
    const void* __restrict__ src, const int* __restrict__ offs,
    const int* __restrict__ csr_col, const float* __restrict__ ss,
    float* __restrict__ agg, const int* __restrict__ flagp, int mode) {
  int node = blockIdx.x * 4 + (threadIdx.x >> 6);
  if (node >= N_NODES) return;
  int lane = threadIdx.x & 63;
  int ch = lane * 2;
  int start = offs[node], end = offs[node + 1];
  float acc0 = 0.f, acc1 = 0.f;
  int bf = *flagp;

  if (mode == 1) {
    const float* h = (const float*)src;
    float sc0 = ss[ch], sc1 = ss[ch + 1];
    float sh0 = ss[DIM + ch], sh1 = ss[DIM + ch + 1];
    int j = start;
    for (; j + 4 <= end; j += 4) {
      int c0 = csr_col[j], c1 = csr_col[j + 1];
      int c2 = csr_col[j + 2], c3 = csr_col[j + 3];
      float2 v0 = *(const float2*)(h + (size_t)c0 * DIM + ch);
      float2 v1 = *(const float2*)(h + (size_t)c1 * DIM + ch);
      float2 v2 = *(const float2*)(h + (size_t)c2 * DIM + ch);
      float2 v3 = *(const float2*)(h + (size_t)c3 * DIM + ch);
      acc0 += fmaxf(v0.x * sc0 + sh0, 0.f) + fmaxf(v1.x * sc0 + sh0, 0.f) +
              fmaxf(v2.x * sc0 + sh0, 0.f) + fmaxf(v3.x * sc0 + sh0, 0.f);
      acc1 += fmaxf(v0.y * sc1 + sh1, 0.f) + fmaxf(v1.y * sc1 + sh1, 0.f) +
              fmaxf(v2.y * sc1 + sh1, 0.f) + fmaxf(v3.y * sc1 + sh1, 0.f);
    }
    for (; j < end; ++j) {
      int c = csr_col[j];
      float2 v = *(const float2*)(h + (size_t)c * DIM + ch);
      acc0 += fmaxf(v.x * sc0 + sh0, 0.f);
      acc1 += fmaxf(v.y * sc1 + sh1, 0.f);
    }
  } else if (bf) {
    const unsigned short* x = (const unsigned short*)src;
    int j = start;
    for (; j + 4 <= end; j += 4) {
      int c0 = csr_col[j], c1 = csr_col[j + 1];
      int c2 = csr_col[j + 2], c3 = csr_col[j + 3];
      unsigned u0 = *(const unsigned*)(x + (size_t)c0 * DIM + ch);
      unsigned u1 = *(const unsigned*)(x + (size_t)c1 * DIM + ch);
      unsigned u2 = *(const unsigned*)(x + (size_t)c2 * DIM + ch);
      unsigned u3 = *(const unsigned*)(x + (size_t)c3 * DIM + ch);
      acc0 += bf2f((unsigned short)u0) + bf2f((unsigned short)u1) +
              bf2f((unsigned short)u2) + bf2f((unsigned short)u3);
      acc1 += bf2f((unsigned short)(u0 >> 16)) + bf2f((unsigned short)(u1 >> 16)) +
              bf2f((unsigned short)(u2 >> 16)) + bf2f((unsigned short)(u3 >> 16));
    }
    for (; j < end; ++j) {
      int c = csr_col[j];
      unsigned u = *(const unsigned*)(x + (size_t)c * DIM + ch);
      acc0 += bf2f((unsigned short)u);
      acc1 += bf2f((unsigned short)(u >> 16));
    }
  } else {
    const float* x = (const float*)src;
    for (int j = start; j < end; ++j) {
      int c = csr_col[j];
      float2 v = *(const float2*)(x + (size_t)c * DIM + ch);
      acc0 += v.x;
      acc1 += v.y;
    }
  }
  *(float2*)(agg + (size_t)node * DIM + ch) = make_float2(acc0, acc1);
}

// ---- BN finalize: (sum, sumsq) -> per-channel scale/shift ----
__global__ void bn_fin_kernel(const float* __restrict__ stats,
                              const float* __restrict__ g,
                              const float* __restrict__ be,
                              float* __restrict__ ss) {
  int c = threadIdx.x;
  const float invN = 1.0f / (float)N_NODES;
  float m = stats[c] * invN;
  float v = stats[DIM + c] * invN - m * m;
  float scale = g[c] * rsqrtf(v + BN_EPS);
  ss[c] = scale;
  ss[DIM + c] = be[c] - m * scale;
}

// ---- tiled GEMM: C[32 x 128] = op(A) @ W + bias, optional fused BN stats ----
// NOTE: C may alias agg — each block reads its 32 rows fully before storing.
__global__ __launch_bounds__(256) void gemm_kernel(
    const void* __restrict__ Ap, const float* __restrict__ agg,
    const float* __restrict__ W, const float* __restrict__ bias,
    const float* __restrict__ ss, void* __restrict__ Cp,
    float* __restrict__ stats, const int* __restrict__ flagp,
    int a_input, int add_agg, int transform, int out_ext, int do_stats) {
  __shared__ float AsT[128 * 36];  // A tile transposed [k][row], stride 36
  const int tid = threadIdx.x;
  const int row0 = blockIdx.x * 32;
  const int bf = *flagp;

  for (int i = 0; i < 4; ++i) {
    int idx4 = tid + i * 256;
    int lrow = idx4 >> 5;
    int ch = (idx4 & 31) * 4;
    int grow = row0 + lrow;
    float4 v = make_float4(0.f, 0.f, 0.f, 0.f);
    if (grow < N_NODES) {
      if (a_input && bf) {
        const unsigned short* A = (const unsigned short*)Ap;
        ushort4 u = *(const ushort4*)(A + (size_t)grow * DIM + ch);
        v = make_float4(bf2f(u.x), bf2f(u.y), bf2f(u.z), bf2f(u.w));
      } else {
        v = *(const float4*)((const float*)Ap + (size_t)grow * DIM + ch);
      }
      if (transform) {
        float4 sc = *(const float4*)(ss + ch);
        float4 sh = *(const float4*)(ss + DIM + ch);
        v.x = fmaxf(v.x * sc.x + sh.x, 0.f);
        v.y = fmaxf(v.y * sc.y + sh.y, 0.f);
        v.z = fmaxf(v.z * sc.z + sh.z, 0.f);
        v.w = fmaxf(v.w * sc.w + sh.w, 0.f);
      }
      if (add_agg) {
        float4 a = *(const float4*)(agg + (size_t)grow * DIM + ch);
        v.x += a.x; v.y += a.y; v.z += a.z; v.w += a.w;
      }
    }
    AsT[(ch + 0) * 36 + lrow] = v.x;
    AsT[(ch + 1) * 36 + lrow] = v.y;
    AsT[(ch + 2) * 36 + lrow] = v.z;
    AsT[(ch + 3) * 36 + lrow] = v.w;
  }
  __syncthreads();

  const int rg = tid >> 5, cg = tid & 31;
  const int r0 = rg * 4, c0 = cg * 4;
  float acc[4][4] = {};
  const float* wp = W + c0;
#pragma unroll 8
  for (int k = 0; k < 128; ++k) {
    float4 a = *(const float4*)(&AsT[k * 36 + r0]);
    float4 b = *(const float4*)(wp + k * 128);
    acc[0][0] = fmaf(a.x, b.x, acc[0][0]);
    acc[0][1] = fmaf(a.x, b.y, acc[0][1]);
    acc[0][2] = fmaf(a.x, b.z, acc[0][2]);
    acc[0][3] = fmaf(a.x, b.w, acc[0][3]);
    acc[1][0] = fmaf(a.y, b.x, acc[1][0]);
    acc[1][1] = fmaf(a.y, b.y, acc[1][1]);
    acc[1][2] = fmaf(a.y, b.z, acc[1][2]);
    acc[1][3] = fmaf(a.y, b.w, acc[1][3]);
    acc[2][0] = fmaf(a.z, b.x, acc[2][0]);
    acc[2][1] = fmaf(a.z, b.y, acc[2][1]);
    acc[2][2] = fmaf(a.z, b.z, acc[2][2]);
    acc[2][3] = fmaf(a.z, b.w, acc[2][3]);
    acc[3][0] = fmaf(a.w, b.x, acc[3][0]);
    acc[3][1] = fmaf(a.w, b.y, acc[3][1]);
    acc[3][2] = fmaf(a.w, b.z, acc[3][2]);
    acc[3][3] = fmaf(a.w, b.w, acc[3][3]);
  }

  float4 bb = *(const float4*)(bias + c0);
  for (int i = 0; i < 4; ++i) {
    acc[i][0] += bb.x; acc[i][1] += bb.y; acc[i][2] += bb.z; acc[i][3] += bb.w;
  }

  for (int i = 0; i < 4; ++i) {
    int grow = row0 + r0 + i;
    if (grow < N_NODES) {
      if (out_ext && bf) {
        ushort4 o;
        o.x = f2bf(acc[i][0]); o.y = f2bf(acc[i][1]);
        o.z = f2bf(acc[i][2]); o.w = f2bf(acc[i][3]);
        *(ushort4*)((unsigned short*)Cp + (size_t)grow * DIM + c0) = o;
      } else {
        *(float4*)((float*)Cp + (size_t)grow * DIM + c0) =
            make_float4(acc[i][0], acc[i][1], acc[i][2], acc[i][3]);
      }
    }
  }

  if (do_stats) {
    __syncthreads();  // done reading AsT; reuse as reduction scratch
    float* reds = AsT;         // [8][128]
    float* redq = AsT + 1024;  // [8][128]
    for (int j = 0; j < 4; ++j) {
      float s = 0.f, q = 0.f;
      for (int i = 0; i < 4; ++i) {
        if (row0 + r0 + i < N_NODES) {
          float t = acc[i][j];
          s += t; q += t * t;
        }
      }
      reds[rg * 128 + c0 + j] = s;
      redq[rg * 128 + c0 + j] = q;
    }
    __syncthreads();
    if (tid < 128) {
      float s = 0.f, q = 0.f;
      for (int g8 = 0; g8 < 8; ++g8) {
        s += reds[g8 * 128 + tid];
        q += redq[g8 * 128 + tid];
      }
      unsafeAtomicAdd(&stats[tid], s);
      unsafeAtomicAdd(&stats[DIM + tid], q);
    }
  }
}

extern "C" void kernel_launch(void* const* d_in, const int* in_sizes, int n_in,
                              void* d_out, int out_size, void* d_ws, size_t ws_size,
                              hipStream_t stream) {
  const void* x  = d_in[0];
  const int* row = (const int*)d_in[1];
  const int* col = (const int*)d_in[2];

  const size_t ND = (size_t)N_NODES * DIM;
  float* ws    = (float*)d_ws;
  float* buf0  = ws;                   // ND (agg0 -> h1 -> agg1 -> h3)
  float* h2    = buf0 + ND;            // ND
  float* P     = h2 + ND;              // 4*128*128 fp32 weights
  float* PV    = P + 4 * DIM * DIM;    // 10*128 fp32 param vectors
  float* stats = PV + 10 * DIM;        // 3*256
  float* ss    = stats + 3 * 256;      // 3*256
  int*   flag  = (int*)(ss + 3 * 256); // 1 (+pad)
  int*   deg   = flag + 4;             // N
  int*   offs  = deg + N_NODES;        // N+1
  int*   cursor= offs + N_NODES + 1;   // N
  int*   bsum  = cursor + N_NODES;     // 256
  int*   bscan = bsum + 256;           // 256
  int*   csr_col = bscan + 256;        // E

  float* c0_b1f = PV + 0 * DIM; float* c0_gf  = PV + 1 * DIM;
  float* c0_bef = PV + 2 * DIM; float* c0_b2f = PV + 3 * DIM;
  float* bn0_gf = PV + 4 * DIM; float* bn0_bef= PV + 5 * DIM;
  float* c1_b1f = PV + 6 * DIM; float* c1_gf  = PV + 7 * DIM;
  float* c1_bef = PV + 8 * DIM; float* c1_b2f = PV + 9 * DIM;

  const int gemm_grid = (N_NODES + 31) / 32;   // 1563
  const int edge_grid = (N_EDGES + 255) / 256; // 3125
  const int gath_grid = (N_NODES + 3) / 4;     // 12500

  detect_kernel<<<1, 64, 0, stream>>>((const unsigned short*)x, flag);

  wcvt_w_kernel<<<dim3(16, 4), 256, 0, stream>>>(d_in[3], d_in[7], d_in[11],
                                                 d_in[15], P, flag);
  VPtrs vp;
  vp.p[0] = d_in[4];  vp.p[1] = d_in[5];  vp.p[2] = d_in[6];  vp.p[3] = d_in[8];
  vp.p[4] = d_in[9];  vp.p[5] = d_in[10]; vp.p[6] = d_in[12]; vp.p[7] = d_in[13];
  vp.p[8] = d_in[14]; vp.p[9] = d_in[16];
  wcvt_v_kernel<<<1, 256, 0, stream>>>(vp, PV, flag);

  hipMemsetAsync(stats, 0, 3 * 256 * sizeof(float), stream);
  hipMemsetAsync(deg, 0, N_NODES * sizeof(int), stream);

  // ---- CSR build (row-sorted adjacency) ----
  deg_kernel<<<edge_grid, 256, 0, stream>>>(row, deg);
  bsum_kernel<<<NB, 256, 0, stream>>>(deg, bsum);
  bscan_kernel<<<1, 256, 0, stream>>>(bsum, bscan);
  offs_kernel<<<NB, 256, 0, stream>>>(deg, bscan, offs, cursor);
  binedge_kernel<<<edge_grid, 256, 0, stream>>>(row, col, cursor, csr_col);

  // ---- conv0 ----
  gather_kernel<<<gath_grid, 256, 0, stream>>>(x, offs, csr_col, nullptr,
                                               buf0, flag, 0);
  gemm_kernel<<<gemm_grid, 256, 0, stream>>>(
      x, buf0, P + 0 * DIM * DIM, c0_b1f, nullptr, buf0, stats + 0, flag,
      1, 1, 0, 0, 1);
  bn_fin_kernel<<<1, 128, 0, stream>>>(stats + 0, c0_gf, c0_bef, ss + 0);
  gemm_kernel<<<gemm_grid, 256, 0, stream>>>(
      buf0, nullptr, P + 1 * DIM * DIM, c0_b2f, ss + 0, h2, stats + 256, flag,
      0, 0, 1, 0, 1);
  bn_fin_kernel<<<1, 128, 0, stream>>>(stats + 256, bn0_gf, bn0_bef, ss + 256);

  // ---- conv1 ----
  gather_kernel<<<gath_grid, 256, 0, stream>>>(h2, offs, csr_col, ss + 256,
                                               buf0, flag, 1);
  gemm_kernel<<<gemm_grid, 256, 0, stream>>>(
      h2, buf0, P + 2 * DIM * DIM, c1_b1f, ss + 256, buf0, stats + 512, flag,
      0, 1, 1, 0, 1);
  bn_fin_kernel<<<1, 128, 0, stream>>>(stats + 512, c1_gf, c1_bef, ss + 512);
  gemm_kernel<<<gemm_grid, 256, 0, stream>>>(
      buf0, nullptr, P + 3 * DIM * DIM, c1_b2f, ss + 512, d_out, nullptr, flag,
      0, 0, 1, 1, 0);
}

// Round 4
// 535.730 us; speedup vs baseline: 5.6723x; 1.0641x over previous
//
#include <hip/hip_runtime.h>

// GIN 2-layer forward, MI355X (gfx950). Round 4:
//  - GEMMs rewritten on v_mfma_f32_16x16x32_bf16 (bf16 frags, fp32 accum),
//    W pre-packed into B-fragment layout, intermediates stored bf16.
//  - Gather split into 4 channel-slice passes (32 ch = 64B/edge) so the
//    slice (3.2 MB) is per-XCD L2 resident.
// Input dtype (bf16 vs fp32) auto-detected device-side; internal math fp32.

#define N_NODES 50000
#define N_EDGES 800000
#define DIM 128
#define BN_EPS 1e-5f
#define NB 196  // ceil(N_NODES/256)

using bfrag8 = __attribute__((ext_vector_type(8))) short;   // 8 bf16
using accf4  = __attribute__((ext_vector_type(4))) float;   // 4 fp32

__device__ __forceinline__ float bf2f(unsigned short u) {
  union { unsigned u32; float f; } c;
  c.u32 = ((unsigned)u) << 16;
  return c.f;
}
__device__ __forceinline__ unsigned short f2bf(float f) {
  union { float f; unsigned u32; } c;
  c.f = f;
  unsigned u = c.u32;
  return (unsigned short)((u + 0x7fffu + ((u >> 16) & 1u)) >> 16);  // RNE
}

// ---- dtype detector ----
__global__ void detect_kernel(const unsigned short* __restrict__ xs,
                              int* __restrict__ flag) {
  __shared__ int oks[64];
  int t = threadIdx.x;
  unsigned short u = xs[t * 2];
  int e = (u >> 7) & 0xFF;
  oks[t] = ((e >= 96 && e <= 134) || ((u & 0x7FFFu) == 0)) ? 1 : 0;
  __syncthreads();
  if (t == 0) {
    int c = 0;
    for (int i = 0; i < 64; ++i) c += oks[i];
    *flag = (c >= 56) ? 1 : 0;  // 1 = bf16, 0 = fp32
  }
}

// ---- pack the 4 weight matrices into MFMA B-fragment layout (bf16) ----
// frag f = (kt<<9)|(nt<<6)|lane ; element j: W[kt*32+(lane>>4)*8+j][nt*16+(lane&15)]
__global__ __launch_bounds__(256) void packw_kernel(
    const void* w0, const void* w1, const void* w2, const void* w3,
    unsigned short* __restrict__ PW, const int* __restrict__ flagp) {
  int mat = blockIdx.x;
  const void* src = (mat == 0) ? w0 : (mat == 1) ? w1 : (mat == 2) ? w2 : w3;
  unsigned short* dst = PW + (size_t)mat * 16384;
  int bf = *flagp;
  for (int f = threadIdx.x; f < 2048; f += 256) {
    int kt = f >> 9, nt = (f >> 6) & 7, lane = f & 63;
    int kbase = kt * 32 + (lane >> 4) * 8;
    int n = nt * 16 + (lane & 15);
    unsigned short tmp[8];
    for (int j = 0; j < 8; ++j) {
      int idx = (kbase + j) * DIM + n;
      if (bf) tmp[j] = ((const unsigned short*)src)[idx];
      else    tmp[j] = f2bf(((const float*)src)[idx]);
    }
    for (int j = 0; j < 8; ++j) dst[f * 8 + j] = tmp[j];
  }
}

// ---- convert the 10 length-128 param vectors into fp32 ----
struct VPtrs { const void* p[10]; };

__global__ void wcvt_v_kernel(VPtrs vp, float* __restrict__ dst,
                              const int* __restrict__ flagp) {
  int bf = *flagp;
  for (int j = threadIdx.x; j < 10 * DIM; j += 256) {
    int vec = j >> 7, idx = j & 127;
    float v;
    if (bf) v = bf2f(((const unsigned short*)vp.p[vec])[idx]);
    else    v = ((const float*)vp.p[vec])[idx];
    dst[j] = v;
  }
}

// ================= CSR build =================
__global__ __launch_bounds__(256) void deg_kernel(
    const int* __restrict__ row, int* __restrict__ deg) {
  int e = blockIdx.x * 256 + threadIdx.x;
  if (e < N_EDGES) atomicAdd(&deg[row[e]], 1);
}

__global__ __launch_bounds__(256) void bsum_kernel(
    const int* __restrict__ deg, int* __restrict__ bsum) {
  __shared__ int s[256];
  int i = blockIdx.x * 256 + threadIdx.x;
  s[threadIdx.x] = (i < N_NODES) ? deg[i] : 0;
  __syncthreads();
  for (int d = 128; d > 0; d >>= 1) {
    if (threadIdx.x < d) s[threadIdx.x] += s[threadIdx.x + d];
    __syncthreads();
  }
  if (threadIdx.x == 0) bsum[blockIdx.x] = s[0];
}

__global__ __launch_bounds__(256) void bscan_kernel(
    const int* __restrict__ bsum, int* __restrict__ bscan) {
  __shared__ int s[256];
  int t = threadIdx.x;
  int v = (t < NB) ? bsum[t] : 0;
  s[t] = v;
  __syncthreads();
  for (int d = 1; d < 256; d <<= 1) {
    int tv = (t >= d) ? s[t - d] : 0;
    __syncthreads();
    s[t] += tv;
    __syncthreads();
  }
  if (t < NB) bscan[t] = s[t] - v;  // exclusive
}

__global__ __launch_bounds__(256) void offs_kernel(
    const int* __restrict__ deg, const int* __restrict__ bscan,
    int* __restrict__ offs, int* __restrict__ cursor) {
  __shared__ int s[256];
  int t = threadIdx.x;
  int i = blockIdx.x * 256 + t;
  int v = (i < N_NODES) ? deg[i] : 0;
  s[t] = v;
  __syncthreads();
  for (int d = 1; d < 256; d <<= 1) {
    int tv = (t >= d) ? s[t - d] : 0;
    __syncthreads();
    s[t] += tv;
    __syncthreads();
  }
  if (i < N_NODES) {
    int excl = bscan[blockIdx.x] + s[t] - v;
    offs[i] = excl;
    cursor[i] = excl;
    if (i == N_NODES - 1) offs[N_NODES] = excl + v;
  }
}

__global__ __launch_bounds__(256) void binedge_kernel(
    const int* __restrict__ row, const int* __restrict__ col,
    int* __restrict__ cursor, int* __restrict__ csr_col) {
  int e = blockIdx.x * 256 + threadIdx.x;
  if (e < N_EDGES) {
    int slot = atomicAdd(&cursor[row[e]], 1);
    csr_col[slot] = col[e];
  }
}

// ================= channel-sliced gather =================
// One wave per node; 32 channels (this pass); 2 edges in flight (e2 halves),
// unroll-4 per half => up to 8 edges in flight per wave.
// mode 0: src = external input (dtype per flag), no transform.
// mode 1: src = bf16 hidden, apply relu(v*sc+sh) per neighbor.
__global__ __launch_bounds__(256) void gather_pass_kernel(
    const void* __restrict__ src, const int* __restrict__ offs,
    const int* __restrict__ csr_col, const float* __restrict__ ss,
    float* __restrict__ agg, const int* __restrict__ flagp,
    int mode, int pass) {
  int node = blockIdx.x * 4 + (threadIdx.x >> 6);
  if (node >= N_NODES) return;
  int lane = threadIdx.x & 63;
  int c = lane & 31, e2 = lane >> 5;
  int ch = pass * 32 + c;
  int start = offs[node], end = offs[node + 1];
  float acc = 0.f;

  if (mode == 1) {
    const unsigned short* h = (const unsigned short*)src;
    float sc = ss[ch], sh = ss[DIM + ch];
    int j = start + e2;
    for (; j + 6 < end; j += 8) {
      int c0 = csr_col[j], c1 = csr_col[j + 2];
      int c2 = csr_col[j + 4], c3 = csr_col[j + 6];
      float v0 = bf2f(h[(size_t)c0 * DIM + ch]);
      float v1 = bf2f(h[(size_t)c1 * DIM + ch]);
      float v2 = bf2f(h[(size_t)c2 * DIM + ch]);
      float v3 = bf2f(h[(size_t)c3 * DIM + ch]);
      acc += fmaxf(v0 * sc + sh, 0.f) + fmaxf(v1 * sc + sh, 0.f) +
             fmaxf(v2 * sc + sh, 0.f) + fmaxf(v3 * sc + sh, 0.f);
    }
    for (; j < end; j += 2)
      acc += fmaxf(bf2f(h[(size_t)csr_col[j] * DIM + ch]) * sc + sh, 0.f);
  } else if (*flagp) {
    const unsigned short* x = (const unsigned short*)src;
    int j = start + e2;
    for (; j + 6 < end; j += 8) {
      int c0 = csr_col[j], c1 = csr_col[j + 2];
      int c2 = csr_col[j + 4], c3 = csr_col[j + 6];
      acc += bf2f(x[(size_t)c0 * DIM + ch]) + bf2f(x[(size_t)c1 * DIM + ch]) +
             bf2f(x[(size_t)c2 * DIM + ch]) + bf2f(x[(size_t)c3 * DIM + ch]);
    }
    for (; j < end; j += 2) acc += bf2f(x[(size_t)csr_col[j] * DIM + ch]);
  } else {
    const float* x = (const float*)src;
    int j = start + e2;
    for (; j + 6 < end; j += 8) {
      int c0 = csr_col[j], c1 = csr_col[j + 2];
      int c2 = csr_col[j + 4], c3 = csr_col[j + 6];
      acc += x[(size_t)c0 * DIM + ch] + x[(size_t)c1 * DIM + ch] +
             x[(size_t)c2 * DIM + ch] + x[(size_t)c3 * DIM + ch];
    }
    for (; j < end; j += 2) acc += x[(size_t)csr_col[j] * DIM + ch];
  }
  acc += __shfl_down(acc, 32);
  if (e2 == 0) agg[(size_t)node * DIM + ch] = acc;
}

// ---- BN finalize ----
__global__ void bn_fin_kernel(const float* __restrict__ stats,
                              const float* __restrict__ g,
                              const float* __restrict__ be,
                              float* __restrict__ ss) {
  int c = threadIdx.x;
  const float invN = 1.0f / (float)N_NODES;
  float m = stats[c] * invN;
  float v = stats[DIM + c] * invN - m * m;
  float scale = g[c] * rsqrtf(v + BN_EPS);
  ss[c] = scale;
  ss[DIM + c] = be[c] - m * scale;
}

// ================= MFMA GEMM =================
// C[64 x 128] = op(A) @ W + bias ; W pre-packed (PWm), bf16 frags, fp32 acc.
// op(A): load (ext dtype or bf16), optional relu(a*sc+sh), optional +agg(fp32).
// Output: bf16 (internal / external-bf16) via LDS coalesce; fp32-ext direct.
__global__ __launch_bounds__(256) void gemm_kernel(
    const void* __restrict__ Ap, const float* __restrict__ agg,
    const unsigned short* __restrict__ PWm, const float* __restrict__ bias,
    const float* __restrict__ ss, void* __restrict__ Cp,
    float* __restrict__ stats, const int* __restrict__ flagp,
    int a_ext, int add_agg, int transform, int out_ext, int do_stats) {
  __shared__ unsigned short As[64 * 136];  // A tile bf16, stride 136
  __shared__ float red_s[256];
  __shared__ float red_q[256];
  const int tid = threadIdx.x;
  const int row0 = blockIdx.x * 64;
  const int bf = *flagp;

  // ---- stage A (transform fused, rounded to bf16) ----
  for (int i = 0; i < 8; ++i) {
    int G = tid + i * 256;
    int lrow = G >> 5;
    int ch = (G & 31) * 4;
    int grow = row0 + lrow;
    float4 v = make_float4(0.f, 0.f, 0.f, 0.f);
    if (grow < N_NODES) {
      if (a_ext && !bf) {
        v = *(const float4*)((const float*)Ap + (size_t)grow * DIM + ch);
      } else {
        ushort4 u = *(const ushort4*)((const unsigned short*)Ap +
                                      (size_t)grow * DIM + ch);
        v = make_float4(bf2f(u.x), bf2f(u.y), bf2f(u.z), bf2f(u.w));
      }
      if (transform) {
        float4 sc = *(const float4*)(ss + ch);
        float4 sh = *(const float4*)(ss + DIM + ch);
        v.x = fmaxf(v.x * sc.x + sh.x, 0.f);
        v.y = fmaxf(v.y * sc.y + sh.y, 0.f);
        v.z = fmaxf(v.z * sc.z + sh.z, 0.f);
        v.w = fmaxf(v.w * sc.w + sh.w, 0.f);
      }
      if (add_agg) {
        float4 a = *(const float4*)(agg + (size_t)grow * DIM + ch);
        v.x += a.x; v.y += a.y; v.z += a.z; v.w += a.w;
      }
    }
    ushort4 o;
    o.x = f2bf(v.x); o.y = f2bf(v.y); o.z = f2bf(v.z); o.w = f2bf(v.w);
    *(ushort4*)&As[lrow * 136 + ch] = o;
  }
  __syncthreads();

  // ---- MFMA: wave wv does rows [wv*16, wv*16+16), all 128 cols ----
  const int wv = tid >> 6, lane = tid & 63;
  const int quad = lane >> 4, lo = lane & 15;
  accf4 acc[8];
#pragma unroll
  for (int nt = 0; nt < 8; ++nt) {
    acc[nt][0] = 0.f; acc[nt][1] = 0.f; acc[nt][2] = 0.f; acc[nt][3] = 0.f;
  }
#pragma unroll
  for (int kt = 0; kt < 4; ++kt) {
    bfrag8 a = *(const bfrag8*)&As[(wv * 16 + lo) * 136 + kt * 32 + quad * 8];
    const unsigned short* pw = PWm + kt * 4096 + lane * 8;
#pragma unroll
    for (int nt = 0; nt < 8; ++nt) {
      bfrag8 b = *(const bfrag8*)(pw + nt * 512);
      acc[nt] = __builtin_amdgcn_mfma_f32_16x16x32_bf16(a, b, acc[nt], 0, 0, 0);
    }
  }
  __syncthreads();  // all waves done reading As

  // ---- epilogue ----
  if (out_ext && !bf) {
    // fp32 external output: direct (strided) stores
    float* Co = (float*)Cp;
#pragma unroll
    for (int nt = 0; nt < 8; ++nt) {
      float b = bias[nt * 16 + lo];
#pragma unroll
      for (int reg = 0; reg < 4; ++reg) {
        int grow = row0 + wv * 16 + quad * 4 + reg;
        if (grow < N_NODES) Co[(size_t)grow * DIM + nt * 16 + lo] = acc[nt][reg] + b;
      }
    }
  } else {
    // write bf16 C tile back into As, then coalesced store
#pragma unroll
    for (int nt = 0; nt < 8; ++nt) {
      float b = bias[nt * 16 + lo];
#pragma unroll
      for (int reg = 0; reg < 4; ++reg) {
        As[(wv * 16 + quad * 4 + reg) * 136 + nt * 16 + lo] =
            f2bf(acc[nt][reg] + b);
      }
    }
    __syncthreads();
    unsigned short* Co = (unsigned short*)Cp;
    for (int i = 0; i < 8; ++i) {
      int G = tid + i * 256;
      int lrow = G >> 5, ch = (G & 31) * 4;
      int grow = row0 + lrow;
      if (grow < N_NODES)
        *(ushort4*)(Co + (size_t)grow * DIM + ch) =
            *(const ushort4*)&As[lrow * 136 + ch];
    }
    if (do_stats) {
      int c = tid & 127, rh = tid >> 7;
      int rmax = N_NODES - row0;
      if (rmax > 64) rmax = 64;
      int rend = rh * 32 + 32;
      if (rend > rmax) rend = rmax;
      float s = 0.f, q = 0.f;
      for (int r = rh * 32; r < rend; ++r) {
        float v = bf2f(As[r * 136 + c]);
        s += v; q += v * v;
      }
      red_s[tid] = s; red_q[tid] = q;
      __syncthreads();
      if (tid < 128) {
        s = red_s[tid] + red_s[tid + 128];
        q = red_q[tid] + red_q[tid + 128];
        unsafeAtomicAdd(&stats[tid], s);
        unsafeAtomicAdd(&stats[DIM + tid], q);
      }
    }
  }
}

extern "C" void kernel_launch(void* const* d_in, const int* in_sizes, int n_in,
                              void* d_out, int out_size, void* d_ws, size_t ws_size,
                              hipStream_t stream) {
  const void* x  = d_in[0];
  const int* row = (const int*)d_in[1];
  const int* col = (const int*)d_in[2];

  const size_t ND = (size_t)N_NODES * DIM;  // 6.4M elements
  float* agg = (float*)d_ws;                          // ND fp32
  unsigned short* hA = (unsigned short*)(agg + ND);   // ND bf16
  unsigned short* hB = hA + ND;                       // ND bf16
  unsigned short* PW = hB + ND;                       // 4*16384 bf16
  float* PV    = (float*)(PW + 4 * 16384);            // 10*128 fp32
  float* stats = PV + 10 * DIM;                       // 3*256
  float* ss    = stats + 3 * 256;                     // 3*256
  int*   flag  = (int*)(ss + 3 * 256);                // 1 (+pad)
  int*   deg   = flag + 4;                            // N
  int*   offs  = deg + N_NODES;                       // N+1
  int*   cursor = offs + N_NODES + 1;                 // N
  int*   bsum  = cursor + N_NODES;                    // 256
  int*   bscan = bsum + 256;                          // 256
  int*   csr_col = bscan + 256;                       // E

  float* c0_b1f = PV + 0 * DIM; float* c0_gf  = PV + 1 * DIM;
  float* c0_bef = PV + 2 * DIM; float* c0_b2f = PV + 3 * DIM;
  float* bn0_gf = PV + 4 * DIM; float* bn0_bef= PV + 5 * DIM;
  float* c1_b1f = PV + 6 * DIM; float* c1_gf  = PV + 7 * DIM;
  float* c1_bef = PV + 8 * DIM; float* c1_b2f = PV + 9 * DIM;

  const int gemm_grid = (N_NODES + 63) / 64;   // 782
  const int edge_grid = (N_EDGES + 255) / 256; // 3125
  const int gath_grid = (N_NODES + 3) / 4;     // 12500

  detect_kernel<<<1, 64, 0, stream>>>((const unsigned short*)x, flag);
  packw_kernel<<<4, 256, 0, stream>>>(d_in[3], d_in[7], d_in[11], d_in[15],
                                      PW, flag);
  VPtrs vp;
  vp.p[0] = d_in[4];  vp.p[1] = d_in[5];  vp.p[2] = d_in[6];  vp.p[3] = d_in[8];
  vp.p[4] = d_in[9];  vp.p[5] = d_in[10]; vp.p[6] = d_in[12]; vp.p[7] = d_in[13];
  vp.p[8] = d_in[14]; vp.p[9] = d_in[16];
  wcvt_v_kernel<<<1, 256, 0, stream>>>(vp, PV, flag);

  hipMemsetAsync(stats, 0, 3 * 256 * sizeof(float), stream);
  hipMemsetAsync(deg, 0, N_NODES * sizeof(int), stream);

  // ---- CSR build ----
  deg_kernel<<<edge_grid, 256, 0, stream>>>(row, deg);
  bsum_kernel<<<NB, 256, 0, stream>>>(deg, bsum);
  bscan_kernel<<<1, 256, 0, stream>>>(bsum, bscan);
  offs_kernel<<<NB, 256, 0, stream>>>(deg, bscan, offs, cursor);
  binedge_kernel<<<edge_grid, 256, 0, stream>>>(row, col, cursor, csr_col);

  // ---- conv0 ----
  for (int p = 0; p < 4; ++p)
    gather_pass_kernel<<<gath_grid, 256, 0, stream>>>(x, offs, csr_col, nullptr,
                                                      agg, flag, 0, p);
  gemm_kernel<<<gemm_grid, 256, 0, stream>>>(
      x, agg, PW + 0 * 16384, c0_b1f, nullptr, hA, stats + 0, flag,
      1, 1, 0, 0, 1);
  bn_fin_kernel<<<1, 128, 0, stream>>>(stats + 0, c0_gf, c0_bef, ss + 0);
  gemm_kernel<<<gemm_grid, 256, 0, stream>>>(
      hA, nullptr, PW + 1 * 16384, c0_b2f, ss + 0, hB, stats + 256, flag,
      0, 0, 1, 0, 1);
  bn_fin_kernel<<<1, 128, 0, stream>>>(stats + 256, bn0_gf, bn0_bef, ss + 256);

  // ---- conv1 ----
  for (int p = 0; p < 4; ++p)
    gather_pass_kernel<<<gath_grid, 256, 0, stream>>>(hB, offs, csr_col,
                                                      ss + 256, agg, flag, 1, p);
  gemm_kernel<<<gemm_grid, 256, 0, stream>>>(
      hB, agg, PW + 2 * 16384, c1_b1f, ss + 256, hA, stats + 512, flag,
      0, 1, 1, 0, 1);
  bn_fin_kernel<<<1, 128, 0, stream>>>(stats + 512, c1_gf, c1_bef, ss + 512);
  gemm_kernel<<<gemm_grid, 256, 0, stream>>>(
      hA, nullptr, PW + 3 * 16384, c1_b2f, ss + 512, d_out, nullptr, flag,
      0, 0, 1, 1, 0);
}